// Round 3
// baseline (1455.208 us; speedup 1.0000x reference)
//
#include <hip/hip_runtime.h>
#include <hip/hip_bf16.h>
#include <stdint.h>

#define HID 128

// ---------------- mask storage detection ----------------
__global__ void detect_mask_kernel(const unsigned char* __restrict__ p, int nbytes,
                                   int nfloat, int* __restrict__ flags) {
  int stride = blockDim.x * gridDim.x;
  for (int i = blockIdx.x * blockDim.x + threadIdx.x; i < nbytes; i += stride) {
    if ((i & 3) && p[i] != 0) { atomicOr(&flags[0], 1); break; }
  }
  const float* fp = (const float*)p;
  for (int i = blockIdx.x * blockDim.x + threadIdx.x; i < nfloat; i += stride) {
    float f = fp[i];
    if (!(f == 0.0f || f == 1.0f)) { atomicOr(&flags[1], 1); break; }
  }
}

// maskout = mask as 0/1 float; cvec[n][4..7] = h0[n] = mask?x:0; h0s[n] = dis[n]*h0[n]
__global__ void expand_mask_h0(const void* __restrict__ maskp, const float4* __restrict__ x4,
                               const int* __restrict__ flags, const float* __restrict__ dis,
                               float* __restrict__ maskout, float* __restrict__ cvec,
                               float4* __restrict__ h0s, int N) {
  int i = blockIdx.x * blockDim.x + threadIdx.x;
  if (i >= N) return;
  float m;
  if (flags[0] == 0)      m = (((const int*)maskp)[i] != 0) ? 1.f : 0.f;
  else if (flags[1] == 0) m = (((const float*)maskp)[i] != 0.f) ? 1.f : 0.f;
  else                    m = (((const unsigned char*)maskp)[i] != 0) ? 1.f : 0.f;
  maskout[i] = m;
  float4 xv = x4[i];
  float4 h0 = make_float4(m * xv.x, m * xv.y, m * xv.z, m * xv.w);
  float* cv = cvec + (size_t)i * 8;
  cv[4] = h0.x; cv[5] = h0.y; cv[6] = h0.z; cv[7] = h0.w;
  float d = dis[i];
  h0s[i] = make_float4(d * h0.x, d * h0.y, d * h0.z, d * h0.w);
}

// ---------------- CSR build: bucket sort by dst>>6 ----------------
__global__ void bucket_hist_kernel(const int* __restrict__ dst, int* __restrict__ bhist, int E) {
  int e = blockIdx.x * blockDim.x + threadIdx.x;
  if (e < E) atomicAdd(&bhist[dst[e] >> 6], 1);
}

// generic block-scan machinery (1024 elements per block)
__global__ void scan1_kernel(const int* __restrict__ cnt, int* __restrict__ off,
                             int* __restrict__ bsum, int N) {
  __shared__ int wsum[4];
  int t = threadIdx.x, lane = t & 63, w = t >> 6;
  int base = blockIdx.x * 1024 + t * 4;
  int v0 = (base + 0 < N) ? cnt[base + 0] : 0;
  int v1 = (base + 1 < N) ? cnt[base + 1] : 0;
  int v2 = (base + 2 < N) ? cnt[base + 2] : 0;
  int v3 = (base + 3 < N) ? cnt[base + 3] : 0;
  int ts = v0 + v1 + v2 + v3;
  int sc = ts;
  for (int d = 1; d < 64; d <<= 1) {
    int x = __shfl_up(sc, d, 64);
    if (lane >= d) sc += x;
  }
  if (lane == 63) wsum[w] = sc;
  __syncthreads();
  int wo = 0;
  for (int i = 0; i < w; i++) wo += wsum[i];
  int excl = wo + sc - ts;
  if (base + 0 < N) off[base + 0] = excl;
  if (base + 1 < N) off[base + 1] = excl + v0;
  if (base + 2 < N) off[base + 2] = excl + v0 + v1;
  if (base + 3 < N) off[base + 3] = excl + v0 + v1 + v2;
  if (t == 255) bsum[blockIdx.x] = wo + sc;
}

__global__ void scan2_kernel(int* __restrict__ bsum, int nb) {
  if (threadIdx.x == 0 && blockIdx.x == 0) {
    int run = 0;
    for (int i = 0; i < nb; i++) { int v = bsum[i]; bsum[i] = run; run += v; }
  }
}

__global__ void scan3_kernel(int* __restrict__ off, const int* __restrict__ bsum,
                             int* __restrict__ cur, int N, int E) {
  int i = blockIdx.x * blockDim.x + threadIdx.x;
  if (i < N) {
    int o = off[i] + bsum[i >> 10];
    off[i] = o;
    cur[i] = o;
  }
  if (i == 0) off[N] = E;
}

// scatter packed (dstlow<<26 | src) into bucket regions (bcur pre-init to bucket bases)
__global__ void bucket_scatter_kernel(const int* __restrict__ src, const int* __restrict__ dst,
                                      int* __restrict__ bcur, uint32_t* __restrict__ bdata, int E) {
  int e = blockIdx.x * blockDim.x + threadIdx.x;
  if (e < E) {
    int d = dst[e];
    int pos = atomicAdd(&bcur[d >> 6], 1);
    bdata[pos] = ((uint32_t)(d & 63) << 26) | (uint32_t)src[e];
  }
}

// per-bucket counting sort: emits csr (globally sorted by dst), off[], dis[]
__global__ void bucket_sort_kernel(const uint32_t* __restrict__ bdata,
                                   const int* __restrict__ bbase,
                                   int* __restrict__ off, float* __restrict__ dis,
                                   int* __restrict__ csr, int N, int E) {
  __shared__ int cnt_l[64], off_l[64], pos_l[64];
  int b = blockIdx.x, t = threadIdx.x;
  int base = bbase[b], end = bbase[b + 1];
  if (t < 64) { cnt_l[t] = 0; pos_l[t] = 0; }
  __syncthreads();
  for (int i = base + t; i < end; i += 256) {
    atomicAdd(&cnt_l[bdata[i] >> 26], 1);
  }
  __syncthreads();
  if (t < 64) {
    int c = cnt_l[t];
    int sc = c;
    for (int d = 1; d < 64; d <<= 1) {
      int x = __shfl_up(sc, d, 64);
      if (t >= d) sc += x;
    }
    int excl = sc - c;
    off_l[t] = excl;
    int dstn = b * 64 + t;
    if (dstn < N) {
      off[dstn] = base + excl;
      dis[dstn] = rsqrtf((float)c + 1.0f);
    }
  }
  if (b == 0 && t == 255) off[N] = E;
  __syncthreads();
  for (int i = base + t; i < end; i += 256) {
    uint32_t v = bdata[i];
    int dl = v >> 26;
    int idx = atomicAdd(&pos_l[dl], 1);
    csr[base + off_l[dl] + idx] = (int)(v & 0x03FFFFFFu);
  }
}

// ---------------- fallback CSR build (N > 2^26 only) ----------------
__global__ void hist_kernel(const int* __restrict__ dst, int* __restrict__ cnt, int E) {
  int e = blockIdx.x * blockDim.x + threadIdx.x;
  if (e < E) atomicAdd(&cnt[dst[e]], 1);
}

__global__ void dis_kernel(const int* __restrict__ cnt, float* __restrict__ dis, int N) {
  int i = blockIdx.x * blockDim.x + threadIdx.x;
  if (i < N) dis[i] = rsqrtf((float)cnt[i] + 1.0f);
}

__global__ void fill_kernel(const int* __restrict__ src, const int* __restrict__ dst,
                            int* __restrict__ cur, int* __restrict__ csr, int E) {
  int e = blockIdx.x * blockDim.x + threadIdx.x;
  if (e < E) {
    int d = dst[e];
    int pos = atomicAdd(&cur[d], 1);
    csr[pos] = src[e];
  }
}

// ---------------- layer 0 aggregation (4-dim, pre-scaled operand) ----------------
__global__ void l0_agg_kernel(const float4* __restrict__ h0s, const float* __restrict__ dis,
                              const int* __restrict__ off, const int* __restrict__ csr,
                              float* __restrict__ cvec, int N) {
  int n = blockIdx.x * blockDim.x + threadIdx.x;
  if (n >= N) return;
  float4 a = h0s[n];
  int e0 = off[n], e1 = off[n + 1];
  int i = e0;
  for (; i + 4 <= e1; i += 4) {
    int s0 = csr[i], s1 = csr[i + 1], s2 = csr[i + 2], s3 = csr[i + 3];
    float4 v0 = h0s[s0], v1 = h0s[s1], v2 = h0s[s2], v3 = h0s[s3];
    a.x += v0.x + v1.x + v2.x + v3.x;
    a.y += v0.y + v1.y + v2.y + v3.y;
    a.z += v0.z + v1.z + v2.z + v3.z;
    a.w += v0.w + v1.w + v2.w + v3.w;
  }
  for (; i < e1; i++) {
    float4 v = h0s[csr[i]];
    a.x += v.x; a.y += v.y; a.z += v.z; a.w += v.w;
  }
  float dn = dis[n];
  float* cv = cvec + (size_t)n * 8;
  cv[0] = dn * a.x; cv[1] = dn * a.y; cv[2] = dn * a.z; cv[3] = dn * a.w;
}

// h1 = relu(agg0@W0 + b0 + h0@resW + res_b); also hb = bf16(dis*h1)
__global__ void l0_combine_kernel(const float* __restrict__ cvec, const float* __restrict__ W0,
                                  const float* __restrict__ b0, const float* __restrict__ resW,
                                  const float* __restrict__ resb, const float* __restrict__ dis,
                                  float* __restrict__ h1, __hip_bfloat16* __restrict__ hbout) {
  int idx = blockIdx.x * blockDim.x + threadIdx.x;
  int n = idx >> 7, c = idx & 127;
  const float* cv = cvec + (size_t)n * 8;
  float acc = b0[c] + resb[c];
#pragma unroll
  for (int k = 0; k < 4; k++) {
    acc += cv[k] * W0[k * HID + c];
    acc += cv[4 + k] * resW[k * HID + c];
  }
  float v = fmaxf(acc, 0.0f);
  h1[idx] = v;
  if (hbout) hbout[idx] = __float2bfloat16(dis[n] * v);
}

// ---------------- 128-dim aggregation, bf16 pre-scaled gather ----------------
__global__ void agg_hid_bf16_kernel(const uint32_t* __restrict__ hb, const float* __restrict__ dis,
                                    const int* __restrict__ off, const int* __restrict__ csr,
                                    float* __restrict__ out, int N) {
  int node = blockIdx.x * 4 + (threadIdx.x >> 6);
  int lane = threadIdx.x & 63;
  if (node >= N) return;
  uint32_t w = hb[(size_t)node * 64 + lane];
  float a0 = __uint_as_float(w << 16);
  float a1 = __uint_as_float(w & 0xffff0000u);
  int e0 = off[node], e1 = off[node + 1];
  int i = e0;
  for (; i + 4 <= e1; i += 4) {
    int s0 = csr[i], s1 = csr[i + 1], s2 = csr[i + 2], s3 = csr[i + 3];
    uint32_t w0 = hb[(size_t)s0 * 64 + lane];
    uint32_t w1 = hb[(size_t)s1 * 64 + lane];
    uint32_t w2 = hb[(size_t)s2 * 64 + lane];
    uint32_t w3 = hb[(size_t)s3 * 64 + lane];
    a0 += __uint_as_float(w0 << 16);  a1 += __uint_as_float(w0 & 0xffff0000u);
    a0 += __uint_as_float(w1 << 16);  a1 += __uint_as_float(w1 & 0xffff0000u);
    a0 += __uint_as_float(w2 << 16);  a1 += __uint_as_float(w2 & 0xffff0000u);
    a0 += __uint_as_float(w3 << 16);  a1 += __uint_as_float(w3 & 0xffff0000u);
  }
  for (; i < e1; i++) {
    uint32_t ww = hb[(size_t)csr[i] * 64 + lane];
    a0 += __uint_as_float(ww << 16);
    a1 += __uint_as_float(ww & 0xffff0000u);
  }
  float dn = dis[node];
  *(float2*)&out[(size_t)node * HID + 2 * lane] = make_float2(dn * a0, dn * a1);
}

// f32 fallback aggregation
__global__ void agg_hid_kernel(const float* __restrict__ h, const float* __restrict__ dis,
                               const int* __restrict__ off, const int* __restrict__ csr,
                               float* __restrict__ out, int N) {
  int node = blockIdx.x * 4 + (threadIdx.x >> 6);
  int lane = threadIdx.x & 63;
  if (node >= N) return;
  float dn = dis[node];
  const float* hrow = h + (size_t)node * HID;
  float a0 = dn * hrow[lane];
  float a1 = dn * hrow[lane + 64];
  int e0 = off[node], e1 = off[node + 1];
  for (int i = e0; i < e1; i++) {
    int s = csr[i];
    float d = dis[s];
    const float* hs = h + (size_t)s * HID;
    a0 += d * hs[lane];
    a1 += d * hs[lane + 64];
  }
  out[(size_t)node * HID + lane] = dn * a0;
  out[(size_t)node * HID + lane + 64] = dn * a1;
}

// ---------------- h_next = relu(agg @ W + b + h_res), in-place over agg ----------------
__global__ void gemm_resid_relu_kernel(float* __restrict__ ag, const float* __restrict__ hres,
                                       const float* __restrict__ W, const float* __restrict__ b,
                                       const float* __restrict__ dis,
                                       __hip_bfloat16* __restrict__ hbout, int N) {
  __shared__ float ash[64 * HID];
  int t = threadIdx.x;
  int n0 = blockIdx.x * 64;
  for (int i = t; i < 64 * HID; i += 256) {
    int gn = n0 + (i >> 7);
    ash[i] = (gn < N) ? ag[(size_t)gn * HID + (i & 127)] : 0.0f;
  }
  __syncthreads();
  int tc = t & 31;
  int tn = t >> 5;
  float acc[8][4];
#pragma unroll
  for (int j = 0; j < 8; j++)
#pragma unroll
    for (int q = 0; q < 4; q++) acc[j][q] = 0.0f;

  for (int k = 0; k < HID; k += 4) {
    float4 w0 = *(const float4*)&W[(k + 0) * HID + tc * 4];
    float4 w1 = *(const float4*)&W[(k + 1) * HID + tc * 4];
    float4 w2 = *(const float4*)&W[(k + 2) * HID + tc * 4];
    float4 w3 = *(const float4*)&W[(k + 3) * HID + tc * 4];
#pragma unroll
    for (int j = 0; j < 8; j++) {
      float4 a = *(const float4*)&ash[(tn * 8 + j) * HID + k];
      acc[j][0] += a.x * w0.x + a.y * w1.x + a.z * w2.x + a.w * w3.x;
      acc[j][1] += a.x * w0.y + a.y * w1.y + a.z * w2.y + a.w * w3.y;
      acc[j][2] += a.x * w0.z + a.y * w1.z + a.z * w2.z + a.w * w3.z;
      acc[j][3] += a.x * w0.w + a.y * w1.w + a.z * w2.w + a.w * w3.w;
    }
  }
  float4 bv = *(const float4*)&b[tc * 4];
#pragma unroll
  for (int j = 0; j < 8; j++) {
    int gn = n0 + tn * 8 + j;
    if (gn < N) {
      float4 hv = *(const float4*)&hres[(size_t)gn * HID + tc * 4];
      float4 o;
      o.x = fmaxf(acc[j][0] + bv.x + hv.x, 0.0f);
      o.y = fmaxf(acc[j][1] + bv.y + hv.y, 0.0f);
      o.z = fmaxf(acc[j][2] + bv.z + hv.z, 0.0f);
      o.w = fmaxf(acc[j][3] + bv.w + hv.w, 0.0f);
      *(float4*)&ag[(size_t)gn * HID + tc * 4] = o;
      if (hbout) {
        float dnn = dis[gn];
        __hip_bfloat162 p01 = __float22bfloat162_rn(make_float2(dnn * o.x, dnn * o.y));
        __hip_bfloat162 p23 = __float22bfloat162_rn(make_float2(dnn * o.z, dnn * o.w));
        *(__hip_bfloat162*)&hbout[(size_t)gn * HID + tc * 4] = p01;
        *(__hip_bfloat162*)&hbout[(size_t)gn * HID + tc * 4 + 2] = p23;
      }
    }
  }
}

// ---------------- final fc ----------------
__global__ void fc_kernel(const float* __restrict__ h3, const float* __restrict__ fcW,
                          const float* __restrict__ fcb, float* __restrict__ out, int N) {
  __shared__ float sh[64 * 130];
  int t = threadIdx.x;
  int n0 = blockIdx.x * 64;
  for (int i = t; i < 64 * HID; i += 256) {
    int n = i >> 7, k = i & 127;
    int gn = n0 + n;
    sh[n * 130 + k] = (gn < N) ? h3[(size_t)gn * HID + k] : 0.0f;
  }
  __syncthreads();
  int nl = t >> 2, j = t & 3;
  float acc = fcb[j];
  for (int k = 0; k < HID; k++) acc += sh[nl * 130 + k] * fcW[k * 4 + j];
  int gn = n0 + nl;
  if (gn < N) out[(size_t)gn * 4 + j] = acc;
}

// ---------------- host ----------------
extern "C" void kernel_launch(void* const* d_in, const int* in_sizes, int n_in,
                              void* d_out, int out_size, void* d_ws, size_t ws_size,
                              hipStream_t stream) {
  const float* x = (const float*)d_in[0];
  const int* edge = (const int*)d_in[1];
  const void* maskp = d_in[2];
  const float* W0 = (const float*)d_in[3];
  const float* b0 = (const float*)d_in[4];
  const float* resW = (const float*)d_in[5];
  const float* resb = (const float*)d_in[6];
  const float* W1 = (const float*)d_in[7];
  const float* b1 = (const float*)d_in[8];
  const float* W2 = (const float*)d_in[9];
  const float* b2 = (const float*)d_in[10];
  const float* fcW = (const float*)d_in[11];
  const float* fcb = (const float*)d_in[12];
  float* out = (float*)d_out;

  int N = in_sizes[0] / 4;
  int E = in_sizes[1] / 2;
  const int* srcp = edge;
  const int* dstp = edge + E;

  char* ws = (char*)d_ws;
  size_t cursor = 0;
  auto alloc = [&](size_t bytes) { char* p = ws + cursor; cursor += (bytes + 511) & ~(size_t)511; return p; };
  int* flags = (int*)alloc(16);
  float* dis = (float*)alloc((size_t)N * 4);
  int* off = (int*)alloc((size_t)(N + 1) * 4);
  int* bsum = (int*)alloc(1024);
  int* csr = (int*)alloc((size_t)E * 4);
  float* h0s = (float*)alloc((size_t)N * 4 * 4);
  float* cvec = (float*)alloc((size_t)N * 8 * 4);
  float* buf0 = (float*)alloc((size_t)N * HID * 4);
  float* buf1 = (float*)alloc((size_t)N * HID * 4);
  size_t base_cursor = cursor;
  __hip_bfloat16* hb = (__hip_bfloat16*)alloc((size_t)N * HID * 2);
  bool use_bf16 = (cursor <= ws_size);
  if (!use_bf16) {
    hb = nullptr;
    if (base_cursor > ws_size) return;
  }

  int nbuckets = (N + 63) >> 6;
  bool use_bucket = (N <= (1 << 26));
  // small/temporary arrays aliased into buf0 (dead until l0_combine writes h1)
  int* bhist = (int*)buf0;
  int* bbase = bhist + (nbuckets + 1);
  int* bcur = bbase + (nbuckets + 1);
  int* cnt = bcur + nbuckets;          // fallback path only
  int* cur = cnt;                      // cnt dead after its scan — reuse
  uint32_t* bdata = (uint32_t*)buf1;   // packed edges, dead before layer-1 agg writes buf1

  int nThreadsN = (N + 255) / 256;
  int gridE = (E + 255) / 256;

  hipMemsetAsync(flags, 0, 16, stream);
  detect_mask_kernel<<<256, 256, 0, stream>>>((const unsigned char*)maskp, N, N / 4, flags);

  if (use_bucket) {
    hipMemsetAsync(bhist, 0, (size_t)(nbuckets + 1) * 4, stream);
    int nb2 = (nbuckets + 1023) / 1024;
    bucket_hist_kernel<<<gridE, 256, 0, stream>>>(dstp, bhist, E);
    scan1_kernel<<<nb2, 256, 0, stream>>>(bhist, bbase, bsum, nbuckets);
    scan2_kernel<<<1, 64, 0, stream>>>(bsum, nb2);
    scan3_kernel<<<(nbuckets + 255) / 256, 256, 0, stream>>>(bbase, bsum, bcur, nbuckets, E);
    bucket_scatter_kernel<<<gridE, 256, 0, stream>>>(srcp, dstp, bcur, bdata, E);
    bucket_sort_kernel<<<nbuckets, 256, 0, stream>>>(bdata, bbase, off, dis, csr, N, E);
  } else {
    hipMemsetAsync(cnt, 0, (size_t)N * 4, stream);
    int nb = (N + 1023) / 1024;
    hist_kernel<<<gridE, 256, 0, stream>>>(dstp, cnt, E);
    dis_kernel<<<nThreadsN, 256, 0, stream>>>(cnt, dis, N);
    scan1_kernel<<<nb, 256, 0, stream>>>(cnt, off, bsum, N);
    scan2_kernel<<<1, 64, 0, stream>>>(bsum, nb);
    scan3_kernel<<<nThreadsN, 256, 0, stream>>>(off, bsum, cur, N, E);
    fill_kernel<<<gridE, 256, 0, stream>>>(srcp, dstp, cur, csr, E);
  }

  expand_mask_h0<<<nThreadsN, 256, 0, stream>>>(maskp, (const float4*)x, flags, dis,
                                                out + (size_t)N * 4, cvec, (float4*)h0s, N);

  // layer 0
  l0_agg_kernel<<<nThreadsN, 256, 0, stream>>>((const float4*)h0s, dis, off, csr, cvec, N);
  l0_combine_kernel<<<(N * HID + 255) / 256, 256, 0, stream>>>(cvec, W0, b0, resW, resb, dis,
                                                               buf0, hb);

  // layer 1
  if (use_bf16)
    agg_hid_bf16_kernel<<<(N + 3) / 4, 256, 0, stream>>>((const uint32_t*)hb, dis, off, csr, buf1, N);
  else
    agg_hid_kernel<<<(N + 3) / 4, 256, 0, stream>>>(buf0, dis, off, csr, buf1, N);
  gemm_resid_relu_kernel<<<(N + 63) / 64, 256, 0, stream>>>(buf1, buf0, W1, b1, dis, hb, N);

  // layer 2
  if (use_bf16)
    agg_hid_bf16_kernel<<<(N + 3) / 4, 256, 0, stream>>>((const uint32_t*)hb, dis, off, csr, buf0, N);
  else
    agg_hid_kernel<<<(N + 3) / 4, 256, 0, stream>>>(buf1, dis, off, csr, buf0, N);
  gemm_resid_relu_kernel<<<(N + 63) / 64, 256, 0, stream>>>(buf0, buf1, W2, b2, dis, nullptr, N);

  // output
  fc_kernel<<<(N + 63) / 64, 256, 0, stream>>>(buf0, fcW, fcb, out, N);
}

// Round 4
// 772.674 us; speedup vs baseline: 1.8833x; 1.8833x over previous
//
#include <hip/hip_runtime.h>
#include <hip/hip_bf16.h>
#include <stdint.h>

#define HID 128
#define NPART 8        // one partition per XCD (blockIdx & 7 -> XCD under round-robin)
#define NCHUNK 256     // chunks per partition; grid = NPART*NCHUNK blocks

// ---------------- mask storage detection ----------------
__global__ void detect_mask_kernel(const unsigned char* __restrict__ p, int nbytes,
                                   int nfloat, int* __restrict__ flags) {
  int stride = blockDim.x * gridDim.x;
  for (int i = blockIdx.x * blockDim.x + threadIdx.x; i < nbytes; i += stride) {
    if ((i & 3) && p[i] != 0) { atomicOr(&flags[0], 1); break; }
  }
  const float* fp = (const float*)p;
  for (int i = blockIdx.x * blockDim.x + threadIdx.x; i < nfloat; i += stride) {
    float f = fp[i];
    if (!(f == 0.0f || f == 1.0f)) { atomicOr(&flags[1], 1); break; }
  }
}

// maskout = mask as 0/1 float; cvec[n][4..7] = h0[n] = mask?x:0; h0s[n] = dis[n]*h0[n]
__global__ void expand_mask_h0(const void* __restrict__ maskp, const float4* __restrict__ x4,
                               const int* __restrict__ flags, const float* __restrict__ dis,
                               float* __restrict__ maskout, float* __restrict__ cvec,
                               float4* __restrict__ h0s, int N) {
  int i = blockIdx.x * blockDim.x + threadIdx.x;
  if (i >= N) return;
  float m;
  if (flags[0] == 0)      m = (((const int*)maskp)[i] != 0) ? 1.f : 0.f;
  else if (flags[1] == 0) m = (((const float*)maskp)[i] != 0.f) ? 1.f : 0.f;
  else                    m = (((const unsigned char*)maskp)[i] != 0) ? 1.f : 0.f;
  maskout[i] = m;
  float4 xv = x4[i];
  float4 h0 = make_float4(m * xv.x, m * xv.y, m * xv.z, m * xv.w);
  float* cv = cvec + (size_t)i * 8;
  cv[4] = h0.x; cv[5] = h0.y; cv[6] = h0.z; cv[7] = h0.w;
  float d = dis[i];
  h0s[i] = make_float4(d * h0.x, d * h0.y, d * h0.z, d * h0.w);
}

// ---------------- CSR build: XCD-partitioned by dst range ----------------
// partition p handles dst in [p*N/NPART, (p+1)*N/NPART); p = blockIdx & 7 so all
// blocks of a partition land on one XCD (round-robin dispatch) -> cnt/cur/csr
// slices stay resident in that XCD's L2 and lines fill before writeback.
__global__ void hist_part_kernel(const int* __restrict__ dst, int* __restrict__ cnt,
                                 int E, int N) {
  int p = blockIdx.x & (NPART - 1);
  int chunk = blockIdx.x >> 3;
  int lo = (int)((long long)p * N / NPART);
  int hi = (int)((long long)(p + 1) * N / NPART);
  int stride = NCHUNK * 256;
  for (int e = chunk * 256 + threadIdx.x; e < E; e += stride) {
    int d = dst[e];
    if (d >= lo && d < hi) atomicAdd(&cnt[d], 1);
  }
}

__global__ void fill_part_kernel(const int* __restrict__ src, const int* __restrict__ dst,
                                 int* __restrict__ cur, int* __restrict__ csr, int E, int N) {
  int p = blockIdx.x & (NPART - 1);
  int chunk = blockIdx.x >> 3;
  int lo = (int)((long long)p * N / NPART);
  int hi = (int)((long long)(p + 1) * N / NPART);
  int stride = NCHUNK * 256;
  for (int e = chunk * 256 + threadIdx.x; e < E; e += stride) {
    int d = dst[e];
    if (d >= lo && d < hi) {
      int pos = atomicAdd(&cur[d], 1);
      csr[pos] = src[e];
    }
  }
}

__global__ void dis_kernel(const int* __restrict__ cnt, float* __restrict__ dis, int N) {
  int i = blockIdx.x * blockDim.x + threadIdx.x;
  if (i < N) dis[i] = rsqrtf((float)cnt[i] + 1.0f);
}

// ---------------- scan machinery (1024 elements per block) ----------------
__global__ void scan1_kernel(const int* __restrict__ cnt, int* __restrict__ off,
                             int* __restrict__ bsum, int N) {
  __shared__ int wsum[4];
  int t = threadIdx.x, lane = t & 63, w = t >> 6;
  int base = blockIdx.x * 1024 + t * 4;
  int v0 = (base + 0 < N) ? cnt[base + 0] : 0;
  int v1 = (base + 1 < N) ? cnt[base + 1] : 0;
  int v2 = (base + 2 < N) ? cnt[base + 2] : 0;
  int v3 = (base + 3 < N) ? cnt[base + 3] : 0;
  int ts = v0 + v1 + v2 + v3;
  int sc = ts;
  for (int d = 1; d < 64; d <<= 1) {
    int x = __shfl_up(sc, d, 64);
    if (lane >= d) sc += x;
  }
  if (lane == 63) wsum[w] = sc;
  __syncthreads();
  int wo = 0;
  for (int i = 0; i < w; i++) wo += wsum[i];
  int excl = wo + sc - ts;
  if (base + 0 < N) off[base + 0] = excl;
  if (base + 1 < N) off[base + 1] = excl + v0;
  if (base + 2 < N) off[base + 2] = excl + v0 + v1;
  if (base + 3 < N) off[base + 3] = excl + v0 + v1 + v2;
  if (t == 255) bsum[blockIdx.x] = wo + sc;
}

__global__ void scan2_kernel(int* __restrict__ bsum, int nb) {
  if (threadIdx.x == 0 && blockIdx.x == 0) {
    int run = 0;
    for (int i = 0; i < nb; i++) { int v = bsum[i]; bsum[i] = run; run += v; }
  }
}

__global__ void scan3_kernel(int* __restrict__ off, const int* __restrict__ bsum,
                             int* __restrict__ cur, int N, int E) {
  int i = blockIdx.x * blockDim.x + threadIdx.x;
  if (i < N) {
    int o = off[i] + bsum[i >> 10];
    off[i] = o;
    cur[i] = o;
  }
  if (i == 0) off[N] = E;
}

// ---------------- layer 0 aggregation (4-dim, pre-scaled operand) ----------------
__global__ void l0_agg_kernel(const float4* __restrict__ h0s, const float* __restrict__ dis,
                              const int* __restrict__ off, const int* __restrict__ csr,
                              float* __restrict__ cvec, int N) {
  int n = blockIdx.x * blockDim.x + threadIdx.x;
  if (n >= N) return;
  float4 a = h0s[n];
  int e0 = off[n], e1 = off[n + 1];
  int i = e0;
  for (; i + 4 <= e1; i += 4) {
    int s0 = csr[i], s1 = csr[i + 1], s2 = csr[i + 2], s3 = csr[i + 3];
    float4 v0 = h0s[s0], v1 = h0s[s1], v2 = h0s[s2], v3 = h0s[s3];
    a.x += v0.x + v1.x + v2.x + v3.x;
    a.y += v0.y + v1.y + v2.y + v3.y;
    a.z += v0.z + v1.z + v2.z + v3.z;
    a.w += v0.w + v1.w + v2.w + v3.w;
  }
  for (; i < e1; i++) {
    float4 v = h0s[csr[i]];
    a.x += v.x; a.y += v.y; a.z += v.z; a.w += v.w;
  }
  float dn = dis[n];
  float* cv = cvec + (size_t)n * 8;
  cv[0] = dn * a.x; cv[1] = dn * a.y; cv[2] = dn * a.z; cv[3] = dn * a.w;
}

// h1 = relu(agg0@W0 + b0 + h0@resW + res_b); also hb = bf16(dis*h1)
__global__ void l0_combine_kernel(const float* __restrict__ cvec, const float* __restrict__ W0,
                                  const float* __restrict__ b0, const float* __restrict__ resW,
                                  const float* __restrict__ resb, const float* __restrict__ dis,
                                  float* __restrict__ h1, __hip_bfloat16* __restrict__ hbout) {
  int idx = blockIdx.x * blockDim.x + threadIdx.x;
  int n = idx >> 7, c = idx & 127;
  const float* cv = cvec + (size_t)n * 8;
  float acc = b0[c] + resb[c];
#pragma unroll
  for (int k = 0; k < 4; k++) {
    acc += cv[k] * W0[k * HID + c];
    acc += cv[4 + k] * resW[k * HID + c];
  }
  float v = fmaxf(acc, 0.0f);
  h1[idx] = v;
  if (hbout) hbout[idx] = __float2bfloat16(dis[n] * v);
}

// ---------------- 128-dim aggregation, bf16 pre-scaled gather ----------------
__global__ void agg_hid_bf16_kernel(const uint32_t* __restrict__ hb, const float* __restrict__ dis,
                                    const int* __restrict__ off, const int* __restrict__ csr,
                                    float* __restrict__ out, int N) {
  int node = blockIdx.x * 4 + (threadIdx.x >> 6);
  int lane = threadIdx.x & 63;
  if (node >= N) return;
  uint32_t w = hb[(size_t)node * 64 + lane];
  float a0 = __uint_as_float(w << 16);
  float a1 = __uint_as_float(w & 0xffff0000u);
  int e0 = off[node], e1 = off[node + 1];
  int i = e0;
  for (; i + 4 <= e1; i += 4) {
    int s0 = csr[i], s1 = csr[i + 1], s2 = csr[i + 2], s3 = csr[i + 3];
    uint32_t w0 = hb[(size_t)s0 * 64 + lane];
    uint32_t w1 = hb[(size_t)s1 * 64 + lane];
    uint32_t w2 = hb[(size_t)s2 * 64 + lane];
    uint32_t w3 = hb[(size_t)s3 * 64 + lane];
    a0 += __uint_as_float(w0 << 16);  a1 += __uint_as_float(w0 & 0xffff0000u);
    a0 += __uint_as_float(w1 << 16);  a1 += __uint_as_float(w1 & 0xffff0000u);
    a0 += __uint_as_float(w2 << 16);  a1 += __uint_as_float(w2 & 0xffff0000u);
    a0 += __uint_as_float(w3 << 16);  a1 += __uint_as_float(w3 & 0xffff0000u);
  }
  for (; i < e1; i++) {
    uint32_t ww = hb[(size_t)csr[i] * 64 + lane];
    a0 += __uint_as_float(ww << 16);
    a1 += __uint_as_float(ww & 0xffff0000u);
  }
  float dn = dis[node];
  *(float2*)&out[(size_t)node * HID + 2 * lane] = make_float2(dn * a0, dn * a1);
}

// f32 fallback aggregation (ws too small for bf16 buffer)
__global__ void agg_hid_kernel(const float* __restrict__ h, const float* __restrict__ dis,
                               const int* __restrict__ off, const int* __restrict__ csr,
                               float* __restrict__ out, int N) {
  int node = blockIdx.x * 4 + (threadIdx.x >> 6);
  int lane = threadIdx.x & 63;
  if (node >= N) return;
  float dn = dis[node];
  const float* hrow = h + (size_t)node * HID;
  float a0 = dn * hrow[lane];
  float a1 = dn * hrow[lane + 64];
  int e0 = off[node], e1 = off[node + 1];
  for (int i = e0; i < e1; i++) {
    int s = csr[i];
    float d = dis[s];
    const float* hs = h + (size_t)s * HID;
    a0 += d * hs[lane];
    a1 += d * hs[lane + 64];
  }
  out[(size_t)node * HID + lane] = dn * a0;
  out[(size_t)node * HID + lane + 64] = dn * a1;
}

// ---------------- h_next = relu(agg @ W + b + h_res), in-place over agg ----------------
__global__ void gemm_resid_relu_kernel(float* __restrict__ ag, const float* __restrict__ hres,
                                       const float* __restrict__ W, const float* __restrict__ b,
                                       const float* __restrict__ dis,
                                       __hip_bfloat16* __restrict__ hbout, int N) {
  __shared__ float ash[64 * HID];
  int t = threadIdx.x;
  int n0 = blockIdx.x * 64;
  for (int i = t; i < 64 * HID; i += 256) {
    int gn = n0 + (i >> 7);
    ash[i] = (gn < N) ? ag[(size_t)gn * HID + (i & 127)] : 0.0f;
  }
  __syncthreads();
  int tc = t & 31;
  int tn = t >> 5;
  float acc[8][4];
#pragma unroll
  for (int j = 0; j < 8; j++)
#pragma unroll
    for (int q = 0; q < 4; q++) acc[j][q] = 0.0f;

  for (int k = 0; k < HID; k += 4) {
    float4 w0 = *(const float4*)&W[(k + 0) * HID + tc * 4];
    float4 w1 = *(const float4*)&W[(k + 1) * HID + tc * 4];
    float4 w2 = *(const float4*)&W[(k + 2) * HID + tc * 4];
    float4 w3 = *(const float4*)&W[(k + 3) * HID + tc * 4];
#pragma unroll
    for (int j = 0; j < 8; j++) {
      float4 a = *(const float4*)&ash[(tn * 8 + j) * HID + k];
      acc[j][0] += a.x * w0.x + a.y * w1.x + a.z * w2.x + a.w * w3.x;
      acc[j][1] += a.x * w0.y + a.y * w1.y + a.z * w2.y + a.w * w3.y;
      acc[j][2] += a.x * w0.z + a.y * w1.z + a.z * w2.z + a.w * w3.z;
      acc[j][3] += a.x * w0.w + a.y * w1.w + a.z * w2.w + a.w * w3.w;
    }
  }
  float4 bv = *(const float4*)&b[tc * 4];
#pragma unroll
  for (int j = 0; j < 8; j++) {
    int gn = n0 + tn * 8 + j;
    if (gn < N) {
      float4 hv = *(const float4*)&hres[(size_t)gn * HID + tc * 4];
      float4 o;
      o.x = fmaxf(acc[j][0] + bv.x + hv.x, 0.0f);
      o.y = fmaxf(acc[j][1] + bv.y + hv.y, 0.0f);
      o.z = fmaxf(acc[j][2] + bv.z + hv.z, 0.0f);
      o.w = fmaxf(acc[j][3] + bv.w + hv.w, 0.0f);
      *(float4*)&ag[(size_t)gn * HID + tc * 4] = o;
      if (hbout) {
        float dnn = dis[gn];
        __hip_bfloat162 p01 = __float22bfloat162_rn(make_float2(dnn * o.x, dnn * o.y));
        __hip_bfloat162 p23 = __float22bfloat162_rn(make_float2(dnn * o.z, dnn * o.w));
        *(__hip_bfloat162*)&hbout[(size_t)gn * HID + tc * 4] = p01;
        *(__hip_bfloat162*)&hbout[(size_t)gn * HID + tc * 4 + 2] = p23;
      }
    }
  }
}

// ---------------- final fc ----------------
__global__ void fc_kernel(const float* __restrict__ h3, const float* __restrict__ fcW,
                          const float* __restrict__ fcb, float* __restrict__ out, int N) {
  __shared__ float sh[64 * 130];
  int t = threadIdx.x;
  int n0 = blockIdx.x * 64;
  for (int i = t; i < 64 * HID; i += 256) {
    int n = i >> 7, k = i & 127;
    int gn = n0 + n;
    sh[n * 130 + k] = (gn < N) ? h3[(size_t)gn * HID + k] : 0.0f;
  }
  __syncthreads();
  int nl = t >> 2, j = t & 3;
  float acc = fcb[j];
  for (int k = 0; k < HID; k++) acc += sh[nl * 130 + k] * fcW[k * 4 + j];
  int gn = n0 + nl;
  if (gn < N) out[(size_t)gn * 4 + j] = acc;
}

// ---------------- host ----------------
extern "C" void kernel_launch(void* const* d_in, const int* in_sizes, int n_in,
                              void* d_out, int out_size, void* d_ws, size_t ws_size,
                              hipStream_t stream) {
  const float* x = (const float*)d_in[0];
  const int* edge = (const int*)d_in[1];
  const void* maskp = d_in[2];
  const float* W0 = (const float*)d_in[3];
  const float* b0 = (const float*)d_in[4];
  const float* resW = (const float*)d_in[5];
  const float* resb = (const float*)d_in[6];
  const float* W1 = (const float*)d_in[7];
  const float* b1 = (const float*)d_in[8];
  const float* W2 = (const float*)d_in[9];
  const float* b2 = (const float*)d_in[10];
  const float* fcW = (const float*)d_in[11];
  const float* fcb = (const float*)d_in[12];
  float* out = (float*)d_out;

  int N = in_sizes[0] / 4;
  int E = in_sizes[1] / 2;
  const int* srcp = edge;
  const int* dstp = edge + E;

  char* ws = (char*)d_ws;
  size_t cursor = 0;
  auto alloc = [&](size_t bytes) { char* p = ws + cursor; cursor += (bytes + 511) & ~(size_t)511; return p; };
  int* flags = (int*)alloc(16);
  int* cnt = (int*)alloc((size_t)N * 4);   // reused as `cur` after scan1
  float* dis = (float*)alloc((size_t)N * 4);
  int* off = (int*)alloc((size_t)(N + 1) * 4);
  int* bsum = (int*)alloc(1024);
  int* csr = (int*)alloc((size_t)E * 4);
  float* h0s = (float*)alloc((size_t)N * 4 * 4);
  float* cvec = (float*)alloc((size_t)N * 8 * 4);
  float* buf0 = (float*)alloc((size_t)N * HID * 4);
  float* buf1 = (float*)alloc((size_t)N * HID * 4);
  size_t base_cursor = cursor;
  __hip_bfloat16* hb = (__hip_bfloat16*)alloc((size_t)N * HID * 2);
  bool use_bf16 = (cursor <= ws_size);
  if (!use_bf16) {
    hb = nullptr;
    if (base_cursor > ws_size) return;
  }

  // zero flags + cnt (adjacent at ws start)
  size_t zbytes = (char*)(cnt + N) - ws;
  hipMemsetAsync(d_ws, 0, zbytes, stream);

  int nThreadsN = (N + 255) / 256;
  int nb = (N + 1023) / 1024;
  int* cur = cnt;  // cnt dead after scan1

  detect_mask_kernel<<<256, 256, 0, stream>>>((const unsigned char*)maskp, N, N / 4, flags);
  hist_part_kernel<<<NPART * NCHUNK, 256, 0, stream>>>(dstp, cnt, E, N);
  dis_kernel<<<nThreadsN, 256, 0, stream>>>(cnt, dis, N);
  scan1_kernel<<<nb, 256, 0, stream>>>(cnt, off, bsum, N);
  scan2_kernel<<<1, 64, 0, stream>>>(bsum, nb);
  scan3_kernel<<<nThreadsN, 256, 0, stream>>>(off, bsum, cur, N, E);
  fill_part_kernel<<<NPART * NCHUNK, 256, 0, stream>>>(srcp, dstp, cur, csr, E, N);

  expand_mask_h0<<<nThreadsN, 256, 0, stream>>>(maskp, (const float4*)x, flags, dis,
                                                out + (size_t)N * 4, cvec, (float4*)h0s, N);

  // layer 0
  l0_agg_kernel<<<nThreadsN, 256, 0, stream>>>((const float4*)h0s, dis, off, csr, cvec, N);
  l0_combine_kernel<<<(N * HID + 255) / 256, 256, 0, stream>>>(cvec, W0, b0, resW, resb, dis,
                                                               buf0, hb);

  // layer 1: agg(h1) -> buf1 ; h2 = relu(buf1@W1 + b1 + buf0) -> buf1 (+ hb)
  if (use_bf16)
    agg_hid_bf16_kernel<<<(N + 3) / 4, 256, 0, stream>>>((const uint32_t*)hb, dis, off, csr, buf1, N);
  else
    agg_hid_kernel<<<(N + 3) / 4, 256, 0, stream>>>(buf0, dis, off, csr, buf1, N);
  gemm_resid_relu_kernel<<<(N + 63) / 64, 256, 0, stream>>>(buf1, buf0, W1, b1, dis, hb, N);

  // layer 2: agg(h2) -> buf0 ; h3 = relu(buf0@W2 + b2 + buf1) -> buf0
  if (use_bf16)
    agg_hid_bf16_kernel<<<(N + 3) / 4, 256, 0, stream>>>((const uint32_t*)hb, dis, off, csr, buf0, N);
  else
    agg_hid_kernel<<<(N + 3) / 4, 256, 0, stream>>>(buf1, dis, off, csr, buf0, N);
  gemm_resid_relu_kernel<<<(N + 63) / 64, 256, 0, stream>>>(buf0, buf1, W2, b2, dis, nullptr, N);

  // output
  fc_kernel<<<(N + 63) / 64, 256, 0, stream>>>(buf0, fcW, fcb, out, N);
}